// Round 18
// baseline (49.834 us; speedup 1.0000x reference)
//
#include <hip/hip_runtime.h>
#include <hip/hip_bf16.h>

// Fused KV-cache append + causal SDPA, flash-attention style, bf16 MFMA.
// B=4 S=128 H=32 D=128 T=2048, start read from input (1024).
// R18: single knob vs R17 (45.4us): z-chunk tile assignment STRIDED ->
//      CONTIGUOUS (block z owns tiles [z*ct,(z+1)*ct)): sequential 16KB-
//      stride KV row streams per block (HBM prefetch-friendly) vs 4MB
//      jumps. Never A/B'd (R4 was contiguous, R7 switched silently).

typedef short bf16x8 __attribute__((ext_vector_type(8)));
typedef float f32x4  __attribute__((ext_vector_type(4)));

constexpr int B = 4, S = 128, H = 32, D = 128, T = 2048;
constexpr int KVBLK = 64;
constexpr int NS = 4;                       // KV chunks
constexpr float SCALE = 0.08838834764831845f;  // 1/sqrt(128)
constexpr float MNEG = -1e30f;              // sentinel (NaN-free vs -inf)

__device__ __forceinline__ short f2bf(float f) {
    return (short)__bfloat16_as_ushort(__float2bfloat16(f));
}
__device__ __forceinline__ unsigned pack_bf2(float a, float b) {
    return (unsigned)(unsigned short)__bfloat16_as_ushort(__float2bfloat16(a))
         | ((unsigned)__bfloat16_as_ushort(__float2bfloat16(b)) << 16);
}

// XOR-swizzled byte offsets into 32KB smem: K rows 256B, V rows 128B.
__device__ __forceinline__ int kswz(int row, int cb) { return row * 256 + (cb ^ ((row & 7) << 4)); }
__device__ __forceinline__ int vswz(int row, int cb) { return 16384 + row * 128 + (cb ^ ((row & 7) << 4)); }

// MODE 0: single-pass, writes out directly (fallback if ws too small).
// MODE 1: KV-chunk partials (unnormalized O, m, l) to workspace.
template<int MODE>
__global__ __launch_bounds__(512, 2) void sdpa_kernel(
    const float* __restrict__ qg, const float* __restrict__ kin,
    const float* __restrict__ vin, const float* __restrict__ kc,
    const float* __restrict__ vc, const int* __restrict__ ip,
    float* __restrict__ out, float* __restrict__ wsO, float2* __restrict__ wsML)
{
    __shared__ __align__(16) char smem[32768];   // K 16KB | V 16KB; epilogue scratch

    const int start = ip[0];
    const int bh = blockIdx.x;
    const int b  = bh >> 5;                 // H = 32
    const int h  = bh & 31;
    const int z  = (MODE == 1) ? blockIdx.z : 0;
    const int t  = threadIdx.x;             // 0..511
    const int w  = t >> 6;                  // wave 0..7
    const int l  = t & 63;
    const int l16 = l & 15;
    const int lg  = l >> 4;                 // 0..3
    const int qi  = w * 16 + l16;           // this lane's q row (0..127)

    // ---- Q fragments (B-operand of swapped QK): wave rows w*16..w*16+15 ----
    const float* qp = qg + (((size_t)b * S + qi) * H + h) * D;
    bf16x8 qfrag[4];
    #pragma unroll
    for (int ks = 0; ks < 4; ++ks) {
        const float* p = qp + ks * 32 + lg * 8;
        #pragma unroll
        for (int i = 0; i < 8; ++i) qfrag[ks][i] = f2bf(p[i]);
    }

    f32x4 oaccT[8];                         // O^T: lane q=l16, d=n*16+lg*4+j
    #pragma unroll
    for (int n = 0; n < 8; ++n) oaccT[n] = {0.f, 0.f, 0.f, 0.f};
    float m = MNEG, ssum = 0.f;             // per-lane (q = l16) stats

    const int kv_end = start + S;           // 1152, 64-aligned
    const int nt     = (kv_end + KVBLK - 1) / KVBLK;    // 18
    int t_lo = 0, t_hi = nt;
    if (MODE == 1) {
        const int ct = (nt + NS - 1) / NS;  // 5
        t_lo = z * ct;
        t_hi = min(t_lo + ct, nt);
    }

    // ---- staging lane mappings (512 threads) ----
    const int kr = t >> 5, c = t & 31;      // K: rows p*16+kr, chunk c
    const int rb = t & 15, cb = t >> 4;     // V: kv 4-row block rb, d-chunk cb

    auto kaddr = [&](int j) -> const float4* {
        return (j < start)
            ? (const float4*)(kc  + (((size_t)b * T + j) * H + h) * (size_t)D)
            : (const float4*)(kin + (((size_t)b * S + (j - start)) * H + h) * (size_t)D);
    };
    auto vaddr = [&](int j) -> const float4* {
        return (j < start)
            ? (const float4*)(vc  + (((size_t)b * T + j) * H + h) * (size_t)D)
            : (const float4*)(vin + (((size_t)b * S + (j - start)) * H + h) * (size_t)D);
    };

    for (int tile = t_lo; tile < t_hi; ++tile) {
        const int j0 = tile * KVBLK;

        // ---- stage K: 4 rows/thread in 2 groups of 2 ----
        #pragma unroll
        for (int g = 0; g < 2; ++g) {
            float4 kt[2];
            #pragma unroll
            for (int p = 0; p < 2; ++p) kt[p] = kaddr(j0 + (g * 2 + p) * 16 + kr)[c];
            #pragma unroll
            for (int p = 0; p < 2; ++p) {
                short4 k4b = { f2bf(kt[p].x), f2bf(kt[p].y), f2bf(kt[p].z), f2bf(kt[p].w) };
                *(short4*)(smem + kswz((g * 2 + p) * 16 + kr, c * 8)) = k4b;
            }
        }
        // ---- stage V: one 4x4 register transpose per thread ----
        {
            float4 a[4];
            #pragma unroll
            for (int kk = 0; kk < 4; ++kk)
                a[kk] = vaddr(j0 + rb * 4 + kk)[cb];
            #pragma unroll
            for (int jj = 0; jj < 4; ++jj) {
                const int d = cb * 4 + jj;
                short4 wv = { f2bf(((const float*)&a[0])[jj]),
                              f2bf(((const float*)&a[1])[jj]),
                              f2bf(((const float*)&a[2])[jj]),
                              f2bf(((const float*)&a[3])[jj]) };
                *(short4*)(smem + vswz(d, rb * 8)) = wv;
            }
        }
        __syncthreads();

        // ---- per-wave skip when entire tile is masked for this wave ----
        if (j0 <= start + w * 16 + 15) {
            // ---- QK^T swapped: sacc[n][j] = S[q=l16][kv=n*16+lg*4+j] ----
            f32x4 sacc[4];
            #pragma unroll
            for (int n = 0; n < 4; ++n) sacc[n] = {0.f, 0.f, 0.f, 0.f};
            #pragma unroll
            for (int n = 0; n < 4; ++n) {
                #pragma unroll
                for (int ks = 0; ks < 4; ++ks) {
                    bf16x8 kfrag = *(const bf16x8*)(smem + kswz(n * 16 + l16, ks * 64 + lg * 16));
                    sacc[n] = __builtin_amdgcn_mfma_f32_16x16x32_bf16(
                        kfrag, qfrag[ks], sacc[n], 0, 0, 0);
                }
            }

            // ---- scale + causal mask + online softmax (row-per-lane) ----
            float pmax = MNEG;
            #pragma unroll
            for (int n = 0; n < 4; ++n) {
                #pragma unroll
                for (int j = 0; j < 4; ++j) {
                    const int kvj = j0 + n * 16 + lg * 4 + j;
                    float s = sacc[n][j] * SCALE;
                    if (kvj > start + qi) s = MNEG;
                    sacc[n][j] = s;
                    pmax = fmaxf(pmax, s);
                }
            }
            pmax = fmaxf(pmax, __shfl_xor(pmax, 16));
            pmax = fmaxf(pmax, __shfl_xor(pmax, 32));
            const float mnew = fmaxf(m, pmax);
            const float corr = __expf(m - mnew);
            m = mnew;

            float tsum = 0.f;
            unsigned plo[4], phi[4];        // packed bf16 P, j={0,1} / {2,3}
            #pragma unroll
            for (int n = 0; n < 4; ++n) {
                float p0 = __expf(sacc[n][0] - m);
                float p1 = __expf(sacc[n][1] - m);
                float p2 = __expf(sacc[n][2] - m);
                float p3 = __expf(sacc[n][3] - m);
                tsum += (p0 + p1) + (p2 + p3);
                plo[n] = pack_bf2(p0, p1);
                phi[n] = pack_bf2(p2, p3);
            }
            tsum += __shfl_xor(tsum, 16);
            tsum += __shfl_xor(tsum, 32);
            ssum = ssum * corr + tsum;
            #pragma unroll
            for (int n = 0; n < 8; ++n) {   // lane-local rescale (q = l16)
                #pragma unroll
                for (int j = 0; j < 4; ++j) oaccT[n][j] *= corr;
            }

            // ---- P redistribution in-register (16 shfl) ----
            const int sA = (((2 * lg)     & 3) << 4) | l16;
            const int sB = (((2 * lg + 1) & 3) << 4) | l16;
            const bool hi = (lg >= 2);
            bf16x8 pfragB[2];
            #pragma unroll
            for (int ks = 0; ks < 2; ++ks) {
                unsigned eA0 = __shfl(plo[2 * ks],     sA), eA1 = __shfl(phi[2 * ks],     sA);
                unsigned fA0 = __shfl(plo[2 * ks + 1], sA), fA1 = __shfl(phi[2 * ks + 1], sA);
                unsigned eB0 = __shfl(plo[2 * ks],     sB), eB1 = __shfl(phi[2 * ks],     sB);
                unsigned fB0 = __shfl(plo[2 * ks + 1], sB), fB1 = __shfl(phi[2 * ks + 1], sB);
                union { unsigned u[4]; bf16x8 v; } cv;
                cv.u[0] = hi ? fA0 : eA0;
                cv.u[1] = hi ? fA1 : eA1;
                cv.u[2] = hi ? fB0 : eB0;
                cv.u[3] = hi ? fB1 : eB1;
                pfragB[ks] = cv.v;
            }

            // ---- PV swapped: O^T[d][q] += V^T[d][kv] * P^T[kv][q] ----
            #pragma unroll
            for (int ks = 0; ks < 2; ++ks) {
                #pragma unroll
                for (int n = 0; n < 8; ++n) {
                    bf16x8 vfrag = *(const bf16x8*)(smem + vswz(n * 16 + l16, ks * 64 + lg * 16));
                    oaccT[n] = __builtin_amdgcn_mfma_f32_16x16x32_bf16(
                        vfrag, pfragB[ks], oaccT[n], 0, 0, 0);
                }
            }
        }
        __syncthreads();
    }

    // ---- epilogue: per-wave 4KB scratch transpose, two 64-d halves ----
    float* scr = (float*)(smem + w * 4096);     // 16 q-rows x 64 d (words)
    const float inv = (MODE == 0) ? 1.0f / ssum : 1.0f;
    #pragma unroll
    for (int half = 0; half < 2; ++half) {
        #pragma unroll
        for (int n2 = 0; n2 < 4; ++n2) {
            const int n = half * 4 + n2;
            #pragma unroll
            for (int j = 0; j < 4; ++j) {
                const int dl = n2 * 16 + lg * 4 + j;    // 0..63 within half
                scr[l16 * 64 + (((dl & ~3) ^ ((l16 & 7) << 2)) | (dl & 3))] =
                    oaccT[n][j] * inv;
            }
        }
        asm volatile("s_waitcnt lgkmcnt(0)" ::: "memory");
        __builtin_amdgcn_sched_barrier(0);
        #pragma unroll
        for (int pass = 0; pass < 4; ++pass) {
            const int r  = pass * 4 + (l >> 4);         // q-row within wave
            const int d0 = (l & 15) * 4;                // within half
            f32x4 val = *(f32x4*)&scr[r * 64 + (d0 ^ ((r & 7) << 2))];
            const int qr = w * 16 + r;
            const int dc = half * 64 + d0;
            if (MODE == 0) {
                *(f32x4*)(out + ((size_t)b * S + qr) * (size_t)(H * D) + h * D + dc) = val;
            } else {
                *(f32x4*)(wsO + ((((size_t)z * B + b) * S + qr) * H + h) * (size_t)D + dc) = val;
            }
        }
        asm volatile("s_waitcnt lgkmcnt(0)" ::: "memory");
        __builtin_amdgcn_sched_barrier(0);
    }
    if (MODE == 1 && lg == 0)
        wsML[(((size_t)z * B + b) * S + qi) * H + h] = make_float2(m, ssum);
}

__global__ __launch_bounds__(256) void combine_kernel(
    const float* __restrict__ wsO, const float2* __restrict__ wsML,
    float* __restrict__ out)
{
    constexpr int R    = B * S * H;         // 16384 rows
    constexpr int TOT4 = R * D / 4;         // float4 elements
    for (int i4 = blockIdx.x * 256 + threadIdx.x; i4 < TOT4;
         i4 += gridDim.x * 256) {
        const int row = i4 >> 5;            // D/4 = 32 float4 per row
        float2 e[NS];
        float M = MNEG;
        #pragma unroll
        for (int cc = 0; cc < NS; ++cc) {
            e[cc] = wsML[(size_t)cc * R + row];
            M = fmaxf(M, e[cc].x);
        }
        float L = 0.f;
        float v0 = 0.f, v1 = 0.f, v2 = 0.f, v3 = 0.f;
        #pragma unroll
        for (int cc = 0; cc < NS; ++cc) {
            const float wgt = __expf(e[cc].x - M);
            L += e[cc].y * wgt;
            float4 tv = ((const float4*)wsO)[(size_t)cc * TOT4 + i4];
            v0 += tv.x * wgt; v1 += tv.y * wgt; v2 += tv.z * wgt; v3 += tv.w * wgt;
        }
        const float inv = 1.0f / L;
        ((float4*)out)[i4] = make_float4(v0 * inv, v1 * inv, v2 * inv, v3 * inv);
    }
}

extern "C" void kernel_launch(void* const* d_in, const int* in_sizes, int n_in,
                              void* d_out, int out_size, void* d_ws, size_t ws_size,
                              hipStream_t stream) {
    const float* q  = (const float*)d_in[0];
    const float* k  = (const float*)d_in[1];
    const float* v  = (const float*)d_in[2];
    const float* kc = (const float*)d_in[3];
    const float* vc = (const float*)d_in[4];
    const int*   ip = (const int*)d_in[5];
    float* out = (float*)d_out;

    const size_t nO  = (size_t)NS * B * S * H * D;
    const size_t nML = (size_t)NS * B * S * H;          // float2 elements
    const size_t need = (nO + 2 * nML) * sizeof(float);

    if (ws_size >= need) {
        float*  wsO  = (float*)d_ws;
        float2* wsML = (float2*)(wsO + nO);
        sdpa_kernel<1><<<dim3(B * H, 1, NS), 512, 0, stream>>>(
            q, k, v, kc, vc, ip, out, wsO, wsML);
        combine_kernel<<<2048, 256, 0, stream>>>(wsO, wsML, out);
    } else {
        sdpa_kernel<0><<<dim3(B * H), 512, 0, stream>>>(
            q, k, v, kc, vc, ip, out, nullptr, nullptr);
    }
}

// Round 19
// 45.355 us; speedup vs baseline: 1.0987x; 1.0987x over previous
//
#include <hip/hip_runtime.h>
#include <hip/hip_bf16.h>

// Fused KV-cache append + causal SDPA, flash-attention style, bf16 MFMA.
// B=4 S=128 H=32 D=128 T=2048, start read from input (1024).
// R19: FINAL — revert to R17/R11 (measured best, 45.4us). R18's contiguous
//      chunking regressed (49.8): strided z-chunks win (better balance;
//      KV is L3-resident so streaming locality bought nothing).
//      Structure: QBLK=128 (8 waves), NS=4 strided KV chunks, 32KB LDS,
//      swapped QK^T/PV (lane-local softmax), in-register P redistribution,
//      fp32 partials + separate combine kernel.

typedef short bf16x8 __attribute__((ext_vector_type(8)));
typedef float f32x4  __attribute__((ext_vector_type(4)));

constexpr int B = 4, S = 128, H = 32, D = 128, T = 2048;
constexpr int KVBLK = 64;
constexpr int NS = 4;                       // KV chunks
constexpr float SCALE = 0.08838834764831845f;  // 1/sqrt(128)
constexpr float MNEG = -1e30f;              // sentinel (NaN-free vs -inf)

__device__ __forceinline__ short f2bf(float f) {
    return (short)__bfloat16_as_ushort(__float2bfloat16(f));
}
__device__ __forceinline__ unsigned pack_bf2(float a, float b) {
    return (unsigned)(unsigned short)__bfloat16_as_ushort(__float2bfloat16(a))
         | ((unsigned)__bfloat16_as_ushort(__float2bfloat16(b)) << 16);
}

// XOR-swizzled byte offsets into 32KB smem: K rows 256B, V rows 128B.
__device__ __forceinline__ int kswz(int row, int cb) { return row * 256 + (cb ^ ((row & 7) << 4)); }
__device__ __forceinline__ int vswz(int row, int cb) { return 16384 + row * 128 + (cb ^ ((row & 7) << 4)); }

// MODE 0: single-pass, writes out directly (fallback if ws too small).
// MODE 1: KV-chunk partials (unnormalized O, m, l) to workspace.
template<int MODE>
__global__ __launch_bounds__(512, 2) void sdpa_kernel(
    const float* __restrict__ qg, const float* __restrict__ kin,
    const float* __restrict__ vin, const float* __restrict__ kc,
    const float* __restrict__ vc, const int* __restrict__ ip,
    float* __restrict__ out, float* __restrict__ wsO, float2* __restrict__ wsML)
{
    __shared__ __align__(16) char smem[32768];   // K 16KB | V 16KB; epilogue scratch

    const int start = ip[0];
    const int bh = blockIdx.x;
    const int b  = bh >> 5;                 // H = 32
    const int h  = bh & 31;
    const int z  = (MODE == 1) ? blockIdx.z : 0;
    const int t  = threadIdx.x;             // 0..511
    const int w  = t >> 6;                  // wave 0..7
    const int l  = t & 63;
    const int l16 = l & 15;
    const int lg  = l >> 4;                 // 0..3
    const int qi  = w * 16 + l16;           // this lane's q row (0..127)

    // ---- Q fragments (B-operand of swapped QK): wave rows w*16..w*16+15 ----
    const float* qp = qg + (((size_t)b * S + qi) * H + h) * D;
    bf16x8 qfrag[4];
    #pragma unroll
    for (int ks = 0; ks < 4; ++ks) {
        const float* p = qp + ks * 32 + lg * 8;
        #pragma unroll
        for (int i = 0; i < 8; ++i) qfrag[ks][i] = f2bf(p[i]);
    }

    f32x4 oaccT[8];                         // O^T: lane q=l16, d=n*16+lg*4+j
    #pragma unroll
    for (int n = 0; n < 8; ++n) oaccT[n] = {0.f, 0.f, 0.f, 0.f};
    float m = MNEG, ssum = 0.f;             // per-lane (q = l16) stats

    const int kv_end = start + S;           // 1152, 64-aligned
    const int nt     = (kv_end + KVBLK - 1) / KVBLK;    // 18
    const int tstep  = (MODE == 1) ? NS : 1;
    const int t0     = (MODE == 1) ? z : 0;             // strided chunking

    // ---- staging lane mappings (512 threads) ----
    const int kr = t >> 5, c = t & 31;      // K: rows p*16+kr, chunk c
    const int rb = t & 15, cb = t >> 4;     // V: kv 4-row block rb, d-chunk cb

    auto kaddr = [&](int j) -> const float4* {
        return (j < start)
            ? (const float4*)(kc  + (((size_t)b * T + j) * H + h) * (size_t)D)
            : (const float4*)(kin + (((size_t)b * S + (j - start)) * H + h) * (size_t)D);
    };
    auto vaddr = [&](int j) -> const float4* {
        return (j < start)
            ? (const float4*)(vc  + (((size_t)b * T + j) * H + h) * (size_t)D)
            : (const float4*)(vin + (((size_t)b * S + (j - start)) * H + h) * (size_t)D);
    };

    for (int tile = t0; tile < nt; tile += tstep) {
        const int j0 = tile * KVBLK;

        // ---- stage K: 4 rows/thread in 2 groups of 2 ----
        #pragma unroll
        for (int g = 0; g < 2; ++g) {
            float4 kt[2];
            #pragma unroll
            for (int p = 0; p < 2; ++p) kt[p] = kaddr(j0 + (g * 2 + p) * 16 + kr)[c];
            #pragma unroll
            for (int p = 0; p < 2; ++p) {
                short4 k4b = { f2bf(kt[p].x), f2bf(kt[p].y), f2bf(kt[p].z), f2bf(kt[p].w) };
                *(short4*)(smem + kswz((g * 2 + p) * 16 + kr, c * 8)) = k4b;
            }
        }
        // ---- stage V: one 4x4 register transpose per thread ----
        {
            float4 a[4];
            #pragma unroll
            for (int kk = 0; kk < 4; ++kk)
                a[kk] = vaddr(j0 + rb * 4 + kk)[cb];
            #pragma unroll
            for (int jj = 0; jj < 4; ++jj) {
                const int d = cb * 4 + jj;
                short4 wv = { f2bf(((const float*)&a[0])[jj]),
                              f2bf(((const float*)&a[1])[jj]),
                              f2bf(((const float*)&a[2])[jj]),
                              f2bf(((const float*)&a[3])[jj]) };
                *(short4*)(smem + vswz(d, rb * 8)) = wv;
            }
        }
        __syncthreads();

        // ---- per-wave skip when entire tile is masked for this wave ----
        if (j0 <= start + w * 16 + 15) {
            // ---- QK^T swapped: sacc[n][j] = S[q=l16][kv=n*16+lg*4+j] ----
            f32x4 sacc[4];
            #pragma unroll
            for (int n = 0; n < 4; ++n) sacc[n] = {0.f, 0.f, 0.f, 0.f};
            #pragma unroll
            for (int n = 0; n < 4; ++n) {
                #pragma unroll
                for (int ks = 0; ks < 4; ++ks) {
                    bf16x8 kfrag = *(const bf16x8*)(smem + kswz(n * 16 + l16, ks * 64 + lg * 16));
                    sacc[n] = __builtin_amdgcn_mfma_f32_16x16x32_bf16(
                        kfrag, qfrag[ks], sacc[n], 0, 0, 0);
                }
            }

            // ---- scale + causal mask + online softmax (row-per-lane) ----
            float pmax = MNEG;
            #pragma unroll
            for (int n = 0; n < 4; ++n) {
                #pragma unroll
                for (int j = 0; j < 4; ++j) {
                    const int kvj = j0 + n * 16 + lg * 4 + j;
                    float s = sacc[n][j] * SCALE;
                    if (kvj > start + qi) s = MNEG;
                    sacc[n][j] = s;
                    pmax = fmaxf(pmax, s);
                }
            }
            pmax = fmaxf(pmax, __shfl_xor(pmax, 16));
            pmax = fmaxf(pmax, __shfl_xor(pmax, 32));
            const float mnew = fmaxf(m, pmax);
            const float corr = __expf(m - mnew);
            m = mnew;

            float tsum = 0.f;
            unsigned plo[4], phi[4];        // packed bf16 P, j={0,1} / {2,3}
            #pragma unroll
            for (int n = 0; n < 4; ++n) {
                float p0 = __expf(sacc[n][0] - m);
                float p1 = __expf(sacc[n][1] - m);
                float p2 = __expf(sacc[n][2] - m);
                float p3 = __expf(sacc[n][3] - m);
                tsum += (p0 + p1) + (p2 + p3);
                plo[n] = pack_bf2(p0, p1);
                phi[n] = pack_bf2(p2, p3);
            }
            tsum += __shfl_xor(tsum, 16);
            tsum += __shfl_xor(tsum, 32);
            ssum = ssum * corr + tsum;
            #pragma unroll
            for (int n = 0; n < 8; ++n) {   // lane-local rescale (q = l16)
                #pragma unroll
                for (int j = 0; j < 4; ++j) oaccT[n][j] *= corr;
            }

            // ---- P redistribution in-register (16 shfl) ----
            const int sA = (((2 * lg)     & 3) << 4) | l16;
            const int sB = (((2 * lg + 1) & 3) << 4) | l16;
            const bool hi = (lg >= 2);
            bf16x8 pfragB[2];
            #pragma unroll
            for (int ks = 0; ks < 2; ++ks) {
                unsigned eA0 = __shfl(plo[2 * ks],     sA), eA1 = __shfl(phi[2 * ks],     sA);
                unsigned fA0 = __shfl(plo[2 * ks + 1], sA), fA1 = __shfl(phi[2 * ks + 1], sA);
                unsigned eB0 = __shfl(plo[2 * ks],     sB), eB1 = __shfl(phi[2 * ks],     sB);
                unsigned fB0 = __shfl(plo[2 * ks + 1], sB), fB1 = __shfl(phi[2 * ks + 1], sB);
                union { unsigned u[4]; bf16x8 v; } cv;
                cv.u[0] = hi ? fA0 : eA0;
                cv.u[1] = hi ? fA1 : eA1;
                cv.u[2] = hi ? fB0 : eB0;
                cv.u[3] = hi ? fB1 : eB1;
                pfragB[ks] = cv.v;
            }

            // ---- PV swapped: O^T[d][q] += V^T[d][kv] * P^T[kv][q] ----
            #pragma unroll
            for (int ks = 0; ks < 2; ++ks) {
                #pragma unroll
                for (int n = 0; n < 8; ++n) {
                    bf16x8 vfrag = *(const bf16x8*)(smem + vswz(n * 16 + l16, ks * 64 + lg * 16));
                    oaccT[n] = __builtin_amdgcn_mfma_f32_16x16x32_bf16(
                        vfrag, pfragB[ks], oaccT[n], 0, 0, 0);
                }
            }
        }
        __syncthreads();
    }

    // ---- epilogue: per-wave 4KB scratch transpose, two 64-d halves ----
    float* scr = (float*)(smem + w * 4096);     // 16 q-rows x 64 d (words)
    const float inv = (MODE == 0) ? 1.0f / ssum : 1.0f;
    #pragma unroll
    for (int half = 0; half < 2; ++half) {
        #pragma unroll
        for (int n2 = 0; n2 < 4; ++n2) {
            const int n = half * 4 + n2;
            #pragma unroll
            for (int j = 0; j < 4; ++j) {
                const int dl = n2 * 16 + lg * 4 + j;    // 0..63 within half
                scr[l16 * 64 + (((dl & ~3) ^ ((l16 & 7) << 2)) | (dl & 3))] =
                    oaccT[n][j] * inv;
            }
        }
        asm volatile("s_waitcnt lgkmcnt(0)" ::: "memory");
        __builtin_amdgcn_sched_barrier(0);
        #pragma unroll
        for (int pass = 0; pass < 4; ++pass) {
            const int r  = pass * 4 + (l >> 4);         // q-row within wave
            const int d0 = (l & 15) * 4;                // within half
            f32x4 val = *(f32x4*)&scr[r * 64 + (d0 ^ ((r & 7) << 2))];
            const int qr = w * 16 + r;
            const int dc = half * 64 + d0;
            if (MODE == 0) {
                *(f32x4*)(out + ((size_t)b * S + qr) * (size_t)(H * D) + h * D + dc) = val;
            } else {
                *(f32x4*)(wsO + ((((size_t)z * B + b) * S + qr) * H + h) * (size_t)D + dc) = val;
            }
        }
        asm volatile("s_waitcnt lgkmcnt(0)" ::: "memory");
        __builtin_amdgcn_sched_barrier(0);
    }
    if (MODE == 1 && lg == 0)
        wsML[(((size_t)z * B + b) * S + qi) * H + h] = make_float2(m, ssum);
}

__global__ __launch_bounds__(256) void combine_kernel(
    const float* __restrict__ wsO, const float2* __restrict__ wsML,
    float* __restrict__ out)
{
    constexpr int R    = B * S * H;         // 16384 rows
    constexpr int TOT4 = R * D / 4;         // float4 elements
    for (int i4 = blockIdx.x * 256 + threadIdx.x; i4 < TOT4;
         i4 += gridDim.x * 256) {
        const int row = i4 >> 5;            // D/4 = 32 float4 per row
        float2 e[NS];
        float M = MNEG;
        #pragma unroll
        for (int cc = 0; cc < NS; ++cc) {
            e[cc] = wsML[(size_t)cc * R + row];
            M = fmaxf(M, e[cc].x);
        }
        float L = 0.f;
        float v0 = 0.f, v1 = 0.f, v2 = 0.f, v3 = 0.f;
        #pragma unroll
        for (int cc = 0; cc < NS; ++cc) {
            const float wgt = __expf(e[cc].x - M);
            L += e[cc].y * wgt;
            float4 tv = ((const float4*)wsO)[(size_t)cc * TOT4 + i4];
            v0 += tv.x * wgt; v1 += tv.y * wgt; v2 += tv.z * wgt; v3 += tv.w * wgt;
        }
        const float inv = 1.0f / L;
        ((float4*)out)[i4] = make_float4(v0 * inv, v1 * inv, v2 * inv, v3 * inv);
    }
}

extern "C" void kernel_launch(void* const* d_in, const int* in_sizes, int n_in,
                              void* d_out, int out_size, void* d_ws, size_t ws_size,
                              hipStream_t stream) {
    const float* q  = (const float*)d_in[0];
    const float* k  = (const float*)d_in[1];
    const float* v  = (const float*)d_in[2];
    const float* kc = (const float*)d_in[3];
    const float* vc = (const float*)d_in[4];
    const int*   ip = (const int*)d_in[5];
    float* out = (float*)d_out;

    const size_t nO  = (size_t)NS * B * S * H * D;
    const size_t nML = (size_t)NS * B * S * H;          // float2 elements
    const size_t need = (nO + 2 * nML) * sizeof(float);

    if (ws_size >= need) {
        float*  wsO  = (float*)d_ws;
        float2* wsML = (float2*)(wsO + nO);
        sdpa_kernel<1><<<dim3(B * H, 1, NS), 512, 0, stream>>>(
            q, k, v, kc, vc, ip, out, wsO, wsML);
        combine_kernel<<<2048, 256, 0, stream>>>(wsO, wsML, out);
    } else {
        sdpa_kernel<0><<<dim3(B * H), 512, 0, stream>>>(
            q, k, v, kc, vc, ip, out, nullptr, nullptr);
    }
}